// Round 1
// baseline (103.428 us; speedup 1.0000x reference)
//
#include <hip/hip_runtime.h>

// EmbedAtt: out[b,d] = sum_i sigmoid((x_num[b,i]-mean[i])/(std[i]+eps)) * lin_W[i,d]
//                    + sum_i lin_b[i,d]
//                    + sum_c emb[c, x_cat[b,c], d]
// B=65536, CN=CC=16, D=128, V=65. All float arrays fp32, x_cat int32, out fp32.
//
// Structure (v2):
//  - TILE=32 rows/block, grid=2048 (8 blocks/CU): prologue amortized 4x vs v1.
//  - lin_W column quads + lin_b column sums live in REGISTERS per lane
//    (loaded once per block from L2) -> zero LDS traffic for the numeric part.
//  - z (sigmoid) and gather indices for all 32 rows computed in one prologue
//    pass (exact same math as v1 -> identical rounding), ONE barrier per block,
//    then the 4 row-group iterations run barrier-free per wave.
//  - Inner loop per row: 8 uniform-address ds_read_b128 (z+idx broadcast),
//    64 register FMAs, 16 independent L2-hit float4 gathers, 1 float4 store.

constexpr int CN = 16;
constexpr int CC = 16;
constexpr int D  = 128;
constexpr int V  = 65;
constexpr float EPS = 1e-5f;
constexpr int TILE  = 32;   // rows per block
constexpr int ITERS = 4;    // TILE / 8 rows-per-iteration (4 waves x 2 rows)

__global__ __launch_bounds__(256) void embed_att_kernel(
    const float* __restrict__ x_num,   // [B, CN]
    const float* __restrict__ means,   // [CN]
    const float* __restrict__ stds,    // [CN]
    const float* __restrict__ lin_W,   // [CN, D]
    const float* __restrict__ lin_b,   // [CN, D]
    const float* __restrict__ emb,     // [CC, V, D]
    const int*  __restrict__ x_cat,    // [B, CC]
    float* __restrict__ out)           // [B, D]
{
    __shared__ float z_s[TILE * CN];   // 2 KB: sigmoid outputs, all 32 rows
    __shared__ int   idx_s[TILE * CC]; // 2 KB: gather indices, all 32 rows

    const int tid  = threadIdx.x;
    const int row0 = blockIdx.x * TILE;

    // ---- prologue: z + idx for all 32 rows; 2 elements per thread ----
    // flat element e = 2*tid, 2*tid+1 ; row = e>>4, attr = e&15 (same [32][16]
    // layout and identical sigmoid expression as v1 -> bit-identical z).
    {
        const float2 x2 = ((const float2*)(x_num + row0 * CN))[tid];
        const int a0 = (tid & 7) * 2;                // even attr index
        const float2 m2 = *(const float2*)&means[a0];
        const float2 s2 = *(const float2*)&stds[a0];
        float2 z2;
        {
            const float t0 = (x2.x - m2.x) / (s2.x + EPS);
            const float e0 = __builtin_amdgcn_exp2f(t0 * -1.44269504088896340736f);
            z2.x = 1.0f / (1.0f + e0);
            const float t1 = (x2.y - m2.y) / (s2.y + EPS);
            const float e1 = __builtin_amdgcn_exp2f(t1 * -1.44269504088896340736f);
            z2.y = 1.0f / (1.0f + e1);
        }
        ((float2*)z_s)[tid]   = z2;
        ((int2*)idx_s)[tid]   = ((const int2*)(x_cat + row0 * CC))[tid];
    }

    // ---- per-lane: lin_W column quads + bias column sums -> registers ----
    // lane g owns output columns [g*4, g*4+4). 16 float4 = 64 VGPRs, loaded
    // once per block (coalesced 512B per half-wave per i, L2-resident).
    const int g = tid & 31;
    float4 wq[CN];
    float bs0 = 0.f, bs1 = 0.f, bs2 = 0.f, bs3 = 0.f;
#pragma unroll
    for (int i = 0; i < CN; ++i) {
        wq[i] = *(const float4*)&lin_W[i * D + g * 4];
        const float4 b = *(const float4*)&lin_b[i * D + g * 4];
        bs0 += b.x; bs1 += b.y; bs2 += b.z; bs3 += b.w;
    }

    __syncthreads();   // the ONLY barrier: z_s/idx_s ready

    const int wv   = tid >> 6;          // wave 0..3
    const int half = (tid >> 5) & 1;    // row within wave's pair
    const float* __restrict__ embg = emb + g * 4;

#pragma unroll 1
    for (int t = 0; t < ITERS; ++t) {
        const int r   = t * 8 + wv * 2 + half;   // row within tile
        const int row = row0 + r;

        const float4* zr = (const float4*)&z_s[r * CN];   // uniform per half-wave
        const int4*   ir = (const int4*)&idx_s[r * CC];   // uniform per half-wave

        float acc0 = bs0, acc1 = bs1, acc2 = bs2, acc3 = bs3;

        // ---- numeric part: acc += z[i] * lin_W[i, g*4..+3], i ascending ----
#pragma unroll
        for (int k = 0; k < 4; ++k) {
            const float4 z4 = zr[k];
            float4 w;
            w = wq[4*k+0]; acc0 += z4.x*w.x; acc1 += z4.x*w.y; acc2 += z4.x*w.z; acc3 += z4.x*w.w;
            w = wq[4*k+1]; acc0 += z4.y*w.x; acc1 += z4.y*w.y; acc2 += z4.y*w.z; acc3 += z4.y*w.w;
            w = wq[4*k+2]; acc0 += z4.z*w.x; acc1 += z4.z*w.y; acc2 += z4.z*w.z; acc3 += z4.z*w.w;
            w = wq[4*k+3]; acc0 += z4.w*w.x; acc1 += z4.w*w.y; acc2 += z4.w*w.z; acc3 += z4.w*w.w;
        }

        // ---- categorical part: 16 independent L2-hit float4 gathers ----
#pragma unroll
        for (int k = 0; k < 4; ++k) {
            const int4 q = ir[k];
            const float4 e0 = *(const float4*)&embg[((4*k+0)*V + q.x) * D];
            const float4 e1 = *(const float4*)&embg[((4*k+1)*V + q.y) * D];
            const float4 e2 = *(const float4*)&embg[((4*k+2)*V + q.z) * D];
            const float4 e3 = *(const float4*)&embg[((4*k+3)*V + q.w) * D];
            acc0 += e0.x; acc1 += e0.y; acc2 += e0.z; acc3 += e0.w;
            acc0 += e1.x; acc1 += e1.y; acc2 += e1.z; acc3 += e1.w;
            acc0 += e2.x; acc1 += e2.y; acc2 += e2.z; acc3 += e2.w;
            acc0 += e3.x; acc1 += e3.y; acc2 += e3.z; acc3 += e3.w;
        }

        // ---- store: per iter the block writes 8 consecutive rows (4 KB) ----
        float4 o; o.x = acc0; o.y = acc1; o.z = acc2; o.w = acc3;
        *(float4*)&out[row * D + g * 4] = o;
    }
}

extern "C" void kernel_launch(void* const* d_in, const int* in_sizes, int n_in,
                              void* d_out, int out_size, void* d_ws, size_t ws_size,
                              hipStream_t stream) {
    const float* x_num = (const float*)d_in[0];
    const float* means = (const float*)d_in[1];
    const float* stds  = (const float*)d_in[2];
    const float* lin_W = (const float*)d_in[3];
    const float* lin_b = (const float*)d_in[4];
    const float* emb   = (const float*)d_in[5];
    const int*   x_cat = (const int*)d_in[6];
    float* out = (float*)d_out;

    const int nrows = in_sizes[0] / CN;   // B
    const int grid  = nrows / TILE;       // 65536 / 32 = 2048 blocks

    embed_att_kernel<<<grid, 256, 0, stream>>>(x_num, means, stds, lin_W, lin_b,
                                               emb, x_cat, out);
}

// Round 2
// 99.233 us; speedup vs baseline: 1.0423x; 1.0423x over previous
//
#include <hip/hip_runtime.h>

// EmbedAtt: out[b,d] = sum_i sigmoid((x_num[b,i]-mean[i])/(std[i]+eps)) * lin_W[i,d]
//                    + sum_i lin_b[i,d]
//                    + sum_c emb[c, x_cat[b,c], d]
// B=65536, CN=CC=16, D=128, V=65. fp32 everywhere, x_cat int32.
//
// v3 = v1's low-VGPR/high-occupancy regime + v2's amortization:
//  - TILE=32 rows/block (grid 2048): lin_W/lin_b staging traffic 134->33 MB.
//  - lin_W stays in LDS (8 KB) -- NOT registers (v2's wq[16]+16 gathers
//    crossed the 128-VGPR occupancy cliff and regressed; gather latency
//    hiding needs 16 waves/CU more than it needs zero LDS reads).
//  - z/idx read as uniform ds_read_b128 quads (8 LDS instrs/row vs v1's 32).
//  - Per row-iter: issue all 16 L2-hit gathers FIRST, then 64 FMAs off LDS,
//    then fold gather results in. One barrier per block.

constexpr int CN = 16;
constexpr int CC = 16;
constexpr int D  = 128;
constexpr int V  = 65;
constexpr float EPS = 1e-5f;
constexpr int TILE  = 32;   // rows per block
constexpr int ITERS = 4;    // 4 waves x 2 rows per iteration

__global__ __launch_bounds__(256) void embed_att_kernel(
    const float* __restrict__ x_num,   // [B, CN]
    const float* __restrict__ means,   // [CN]
    const float* __restrict__ stds,    // [CN]
    const float* __restrict__ lin_W,   // [CN, D]
    const float* __restrict__ lin_b,   // [CN, D]
    const float* __restrict__ emb,     // [CC, V, D]
    const int*  __restrict__ x_cat,    // [B, CC]
    float* __restrict__ out)           // [B, D]
{
    __shared__ float w_s[CN * D];      // 8 KB  lin_W tile
    __shared__ float bsum_s[D];        // 512 B sum_i lin_b[i,:]
    __shared__ float z_s[TILE * CN];   // 2 KB  sigmoid outputs
    __shared__ int   idx_s[TILE * CC]; // 2 KB  gather indices

    const int tid  = threadIdx.x;
    const int row0 = blockIdx.x * TILE;

    // ---- stage lin_W: 2048 floats = 512 float4, 2 per thread ----
    {
        const float4* w4 = (const float4*)lin_W;
        ((float4*)w_s)[tid]       = w4[tid];
        ((float4*)w_s)[tid + 256] = w4[tid + 256];
    }

    // ---- bias column sums (128 threads, coalesced per i) ----
    if (tid < D) {
        float s = 0.f;
#pragma unroll
        for (int i = 0; i < CN; ++i) s += lin_b[i * D + tid];
        bsum_s[tid] = s;
    }

    // ---- z + idx for all 32 rows; 2 elements per thread ----
    // flat elements e = 2*tid, 2*tid+1 in the [32][16] layout; identical
    // sigmoid expression to v1 -> identical rounding.
    {
        const float2 x2 = ((const float2*)(x_num + row0 * CN))[tid];
        const int a0 = (tid & 7) * 2;
        const float2 m2 = *(const float2*)&means[a0];
        const float2 s2 = *(const float2*)&stds[a0];
        float2 z2;
        const float t0 = (x2.x - m2.x) / (s2.x + EPS);
        const float e0 = __builtin_amdgcn_exp2f(t0 * -1.44269504088896340736f);
        z2.x = 1.0f / (1.0f + e0);
        const float t1 = (x2.y - m2.y) / (s2.y + EPS);
        const float e1 = __builtin_amdgcn_exp2f(t1 * -1.44269504088896340736f);
        z2.y = 1.0f / (1.0f + e1);
        ((float2*)z_s)[tid] = z2;
        ((int2*)idx_s)[tid] = ((const int2*)(x_cat + row0 * CC))[tid];
    }

    __syncthreads();   // the only barrier

    const int g   = tid & 31;            // output column quad
    const int wv  = tid >> 6;            // wave 0..3
    const int half = (tid >> 5) & 1;     // row within wave's pair
    const float4 bq = ((const float4*)bsum_s)[g];
    const float* __restrict__ embg = emb + g * 4;

#pragma unroll 1
    for (int t = 0; t < ITERS; ++t) {
        const int r   = t * 8 + wv * 2 + half;
        const int row = row0 + r;

        const int4*   ir = (const int4*)&idx_s[r * CC];   // uniform per half-wave
        const float4* zr = (const float4*)&z_s[r * CN];   // uniform per half-wave

        // ---- issue all 16 gathers first (latency hides under FMAs) ----
        float4 e[16];
#pragma unroll
        for (int k = 0; k < 4; ++k) {
            const int4 q = ir[k];
            e[4*k+0] = *(const float4*)&embg[((4*k+0)*V + q.x) * D];
            e[4*k+1] = *(const float4*)&embg[((4*k+1)*V + q.y) * D];
            e[4*k+2] = *(const float4*)&embg[((4*k+2)*V + q.z) * D];
            e[4*k+3] = *(const float4*)&embg[((4*k+3)*V + q.w) * D];
        }

        // ---- numeric part off LDS: acc += z[i] * lin_W[i, g*4..+3] ----
        float acc0 = bq.x, acc1 = bq.y, acc2 = bq.z, acc3 = bq.w;
#pragma unroll
        for (int k = 0; k < 4; ++k) {
            const float4 z4 = zr[k];
            float4 w;
            w = ((const float4*)w_s)[(4*k+0)*32 + g];
            acc0 += z4.x*w.x; acc1 += z4.x*w.y; acc2 += z4.x*w.z; acc3 += z4.x*w.w;
            w = ((const float4*)w_s)[(4*k+1)*32 + g];
            acc0 += z4.y*w.x; acc1 += z4.y*w.y; acc2 += z4.y*w.z; acc3 += z4.y*w.w;
            w = ((const float4*)w_s)[(4*k+2)*32 + g];
            acc0 += z4.z*w.x; acc1 += z4.z*w.y; acc2 += z4.z*w.z; acc3 += z4.z*w.w;
            w = ((const float4*)w_s)[(4*k+3)*32 + g];
            acc0 += z4.w*w.x; acc1 += z4.w*w.y; acc2 += z4.w*w.z; acc3 += z4.w*w.w;
        }

        // ---- fold in gather results (ascending c, same order as v1) ----
#pragma unroll
        for (int k = 0; k < 16; ++k) {
            acc0 += e[k].x; acc1 += e[k].y; acc2 += e[k].z; acc3 += e[k].w;
        }

        float4 o; o.x = acc0; o.y = acc1; o.z = acc2; o.w = acc3;
        *(float4*)&out[row * D + g * 4] = o;
    }
}

extern "C" void kernel_launch(void* const* d_in, const int* in_sizes, int n_in,
                              void* d_out, int out_size, void* d_ws, size_t ws_size,
                              hipStream_t stream) {
    const float* x_num = (const float*)d_in[0];
    const float* means = (const float*)d_in[1];
    const float* stds  = (const float*)d_in[2];
    const float* lin_W = (const float*)d_in[3];
    const float* lin_b = (const float*)d_in[4];
    const float* emb   = (const float*)d_in[5];
    const int*   x_cat = (const int*)d_in[6];
    float* out = (float*)d_out;

    const int nrows = in_sizes[0] / CN;   // B
    const int grid  = nrows / TILE;       // 65536 / 32 = 2048 blocks

    embed_att_kernel<<<grid, 256, 0, stream>>>(x_num, means, stds, lin_W, lin_b,
                                               emb, x_cat, out);
}